// Round 12
// baseline (2375.952 us; speedup 1.0000x reference)
//
#include <hip/hip_runtime.h>
#include <math.h>

// ---------------- constants ----------------
#define DTMEM 0.1f   // DT*TAU_MEM_INV
#define DTSYN 0.2f   // DT*TAU_SYN_INV
#define DTTR  0.02f  // DT*TAU_PRE_INV == DT*TAU_POST_INV

static constexpr int B = 32, T = 32;
static constexpr int HD = 60, H1 = 56, HP = 28, H2 = 24;
static constexpr int LD  = HD*HD;   // 3600
static constexpr int L1N = H1*H1;   // 3136
static constexpr int LP  = HP*HP;   // 784
static constexpr int L2N = H2*H2;   // 576

// lif0 state: thread-slot-major [b][og:8][yh:2][i:7][tid:448] float2
static constexpr size_t SST  = (size_t)B*8*2*7*448*2;          // floats (=3,211,264)
// conv2 state: thread-slot-major [b][jg:13][slot:6][tid:192] float4
static constexpr size_t SST2 = (size_t)B*13*6*192*4;           // floats (=1,916,928)

// float offsets (no zero region — carried state handled by t==0 branches)
static constexpr size_t OW1   = 0;                             // 1500
static constexpr size_t OV0   = OW1 + 1500;
static constexpr size_t OI0   = OV0   + SST;
static constexpr size_t OTQ1  = OI0   + SST;
static constexpr size_t OTP1A = OTQ1  + SST;                   // [B,60,60] ping
static constexpr size_t OTP1B = OTP1A + (size_t)B*LD;          // [B,60,60] pong
static constexpr size_t OTP2  = OTP1B + (size_t)B*LD;          // [B,30,28,28]
static constexpr size_t OZ3   = OTP2  + (size_t)B*30*LP;
static constexpr size_t OV1S  = OZ3   + (size_t)B*30*LP;
static constexpr size_t OI1S  = OV1S  + SST2;
static constexpr size_t OTQ2S = OI1S  + SST2;
static constexpr size_t OZ4S  = OTQ2S + SST2;
static constexpr size_t OE2P  = OZ4S  + SST2;                  // [100*30*25] compact
static constexpr size_t OE2M  = OE2P  + 75000;
static constexpr size_t OP1   = OE2M  + 75000;                 // [30][50][64]
static constexpr size_t OG    = OP1   + 96000;                 // [T][3200]
static constexpr size_t OHH   = OG    + (size_t)T*3200;        // [T][500]
static constexpr size_t OW2P  = OHH   + (size_t)T*500;         // [100][30][28] (pad cols loaded-but-unused)
static constexpr size_t OCNZ  = OW2P  + 84000;                 // int[960][4]
static constexpr size_t OTOT  = OCNZ  + 3840;

struct DK { float v[25]; };

// ================= Launch A: z=0 front(t) y-half blocks; z=1 w2-apply(t-1) =========
// front: grid (8 og, 64 = b*2+yh, 2), block 448 = (oo:4, xq:4, y:28).
__global__ __launch_bounds__(448) void k_front(
        const float* __restrict__ x, const float* __restrict__ b1,
        const float* __restrict__ b2, const float* __restrict__ w1c,
        const float* __restrict__ tp1r, float* __restrict__ tp1w,
        float* __restrict__ v0, float* __restrict__ i0, float* __restrict__ tq1,
        float* __restrict__ z3, float* __restrict__ tp2,
        float* __restrict__ part, int* __restrict__ cnz4,
        float* __restrict__ w2p, const float* __restrict__ Ep,
        const float* __restrict__ Em, DK dk, int t) {
    if (blockIdx.z == 1) {
        if (t == 0) return;
        int lb = blockIdx.y*8 + blockIdx.x;
        int e = lb*448 + threadIdx.x;
        if (e < 75000) {
            int j = e / 750, r = e % 750, c = r / 25, p = r % 25;
            size_t f = ((size_t)j*30 + c)*28 + p;
            float w = w2p[f];
            float dwp = 0.004f * fmaxf(1.0f - w, 0.0f) * Ep[e];
            float dwm = 0.003f * fmaxf(w, 0.0f) * Em[e];
            w2p[f] = fminf(fmaxf(w + dwp - dwm, 0.0f), 1.0f);
        }
        return;
    }
    __shared__ __attribute__((aligned(16))) float xsh[36*64];   // x rows [y0, y0+36)
    __shared__ __attribute__((aligned(16))) float zsh[32*60];   // DoG rows [y0, y0+32)
    __shared__ __attribute__((aligned(16))) float tsh[32*60];   // tp1 rows [y0, y0+32)
    __shared__ float red[700];                                   // 7 waves x 100
    __shared__ float wd[100];
    __shared__ int sflags[8];
    int og = blockIdx.x, by = blockIdx.y, tid = threadIdx.x;
    int b = by >> 1, yh = by & 1, y0 = yh*28;
    {
        const float4* xs = (const float4*)(x + ((size_t)t*B + b)*4096) + y0*16;
        for (int i = tid; i < 576; i += 448) ((float4*)xsh)[i] = xs[i];
        if (t > 0) {
            const float4* ts = (const float4*)(tp1r + (size_t)b*LD) + y0*15;
            for (int i = tid; i < 480; i += 448) ((float4*)tsh)[i] = ts[i];
        } else {
            float4 zz = make_float4(0.f, 0.f, 0.f, 0.f);
            for (int i = tid; i < 480; i += 448) ((float4*)tsh)[i] = zz;
        }
    }
    if (tid < 100) {
        int oo2 = tid / 25, p = tid % 25;
        int o2 = og*4 + oo2; if (o2 > 29) o2 = 29;
        wd[tid] = w1c[o2*50 + p] - w1c[o2*50 + 25 + p];
    }
    if (tid < 8) sflags[tid] = 0;
    __syncthreads();
    float bias = b1[0] - b2[0];
    // DoG + tp1 trace on local rows (og==0 persists tp1; overlap rows identical)
    for (int idx = tid; idx < 1920; idx += 448) {
        int lr = idx / 60, c = idx % 60;
        float a = 0.f;
        #pragma unroll
        for (int kh = 0; kh < 5; kh++)
            #pragma unroll
            for (int kw = 0; kw < 5; kw++)
                a = fmaf(dk.v[kh*5+kw], xsh[(lr+kh)*64 + c + kw], a);
        float zv = a + bias;
        zsh[idx] = zv;
        float tp = tsh[idx];
        tp = tp + DTTR*(zv - tp);
        tsh[idx] = tp;
        if (og == 0) tp1w[(size_t)b*LD + (y0 + lr)*60 + c] = tp;
    }
    __syncthreads();
    int oo = tid & 3, xq = (tid >> 2) & 3, y = tid >> 4;   // y local [0,28)
    int o = og*4 + oo, x0 = xq*14;
    bool valid = (o < 30);
    float zn[14], tn[14];
    float zs = 0.f, qs = 0.f;
    bool anym = false;
    if (valid) {
        float acc[14];
        #pragma unroll
        for (int k = 0; k < 14; k++) acc[k] = 0.f;
        #pragma unroll
        for (int kh = 0; kh < 5; kh++) {
            float rr[18];
            const float2* r2 = (const float2*)&zsh[(y+kh)*HD + x0];
            #pragma unroll
            for (int i = 0; i < 9; i++) ((float2*)rr)[i] = r2[i];
            #pragma unroll
            for (int kw = 0; kw < 5; kw++) {
                float w = wd[oo*25 + kh*5 + kw];
                #pragma unroll
                for (int k = 0; k < 14; k++) acc[k] = fmaf(w, rr[k+kw], acc[k]);
            }
        }
        // LIF0 + tq1 in slot-major float2 (coalesced); t==0 uses zero state
        float2* v0p = (float2*)v0;
        float2* i0p = (float2*)i0;
        float2* tq1p = (float2*)tq1;
        size_t sb = ((size_t)((b*8 + og)*2 + yh)*7)*448 + tid;
        #pragma unroll
        for (int i = 0; i < 7; i++) {
            float2 v2, c2, t2;
            if (t > 0) {
                v2 = v0p[sb + (size_t)i*448];
                c2 = i0p[sb + (size_t)i*448];
                t2 = tq1p[sb + (size_t)i*448];
            } else {
                v2 = make_float2(0.f, 0.f); c2 = v2; t2 = v2;
            }
            float2 vn, in, tn2;
            #pragma unroll
            for (int k = 0; k < 2; k++) {
                int e = i*2 + k;
                float vv = k ? v2.y : v2.x, cc = k ? c2.y : c2.x, tt = k ? t2.y : t2.x;
                float vd = vv + DTMEM*(cc - vv);
                float z = (vd > 15.0f) ? 1.0f : 0.0f;
                float vo = (1.0f - z)*vd;
                float io_ = (cc - DTSYN*cc) + acc[e];
                float tq = tt + DTTR*(z - tt);
                if (k) { vn.y = vo; in.y = io_; tn2.y = tq; } else { vn.x = vo; in.x = io_; tn2.x = tq; }
                zn[e] = z; tn[e] = tq;
            }
            v0p[sb + (size_t)i*448] = vn;
            i0p[sb + (size_t)i*448] = in;
            tq1p[sb + (size_t)i*448] = tn2;
        }
        #pragma unroll
        for (int k = 0; k < 14; k++) { zs += zn[k]; qs += tn[k]; }
        float mx[7];
        #pragma unroll
        for (int k = 0; k < 7; k++) mx[k] = fmaxf(zn[2*k], zn[2*k+1]);
        #pragma unroll
        for (int k = 0; k < 7; k++) {
            float pm = __shfl_xor(mx[k], 16, 64);   // y-partner (y^1)
            mx[k] = fmaxf(mx[k], pm);
        }
        if ((y & 1) == 0) {
            int py = yh*14 + (y >> 1);
            size_t pb = ((size_t)(b*30 + o)*HP + py)*HP + xq*7;
            #pragma unroll
            for (int k = 0; k < 7; k++) {
                float m = mx[k];
                anym = anym || (m != 0.f);
                z3[pb + k] = m;
                float tpv = (t > 0) ? tp2[pb + k] : 0.f;
                tp2[pb + k] = tpv + DTTR*(m - tpv);
            }
        }
    }
    if (anym) atomicOr(&sflags[oo*2 + (xq >> 1)], 1);
    int lane = tid & 63, wave = tid >> 6;
    // pass 1: minus correlation (unfold(z0) x tq1_new)
    {
        float a[25];
        #pragma unroll
        for (int p = 0; p < 25; p++) a[p] = 0.f;
        if (valid && qs != 0.f) {
            #pragma unroll
            for (int kh = 0; kh < 5; kh++) {
                float rr[18];
                const float2* r2 = (const float2*)&zsh[(y+kh)*HD + x0];
                #pragma unroll
                for (int i = 0; i < 9; i++) ((float2*)rr)[i] = r2[i];
                #pragma unroll
                for (int kw = 0; kw < 5; kw++)
                    #pragma unroll
                    for (int k = 0; k < 14; k++)
                        a[kh*5+kw] = fmaf(rr[k+kw], tn[k], a[kh*5+kw]);
            }
        }
        #pragma unroll
        for (int q = 0; q < 25; q++) {
            float v = a[q];
            v += __shfl_xor(v, 4, 64);
            v += __shfl_xor(v, 8, 64);
            v += __shfl_xor(v, 16, 64);
            v += __shfl_xor(v, 32, 64);
            if (lane < 4) red[wave*100 + lane*25 + q] = v;
        }
    }
    __syncthreads();
    if (tid < 100) {
        int oo2 = tid / 25, q = tid % 25;
        float s = 0.f;
        #pragma unroll
        for (int w = 0; w < 7; w++) s += red[w*100 + oo2*25 + q];
        int o2 = og*4 + oo2;
        if (o2 < 30) part[((size_t)(o2*50 + 25 + q) << 6) + b*2 + yh] = s;
    }
    if (tid < 8) {
        int o2 = og*4 + (tid >> 1);
        if (o2 < 30) cnz4[(b*30 + o2)*4 + yh*2 + (tid & 1)] = sflags[tid];
    }
    __syncthreads();
    // pass 2: plus correlation (unfold(tp1_new) x z2)
    {
        float a[25];
        #pragma unroll
        for (int p = 0; p < 25; p++) a[p] = 0.f;
        if (valid && zs != 0.f) {
            #pragma unroll
            for (int kh = 0; kh < 5; kh++) {
                float rr[18];
                const float2* r2 = (const float2*)&tsh[(y+kh)*HD + x0];
                #pragma unroll
                for (int i = 0; i < 9; i++) ((float2*)rr)[i] = r2[i];
                #pragma unroll
                for (int kw = 0; kw < 5; kw++)
                    #pragma unroll
                    for (int k = 0; k < 14; k++)
                        a[kh*5+kw] = fmaf(rr[k+kw], zn[k], a[kh*5+kw]);
            }
        }
        #pragma unroll
        for (int q = 0; q < 25; q++) {
            float v = a[q];
            v += __shfl_xor(v, 4, 64);
            v += __shfl_xor(v, 8, 64);
            v += __shfl_xor(v, 16, 64);
            v += __shfl_xor(v, 32, 64);
            if (lane < 4) red[wave*100 + lane*25 + q] = v;
        }
    }
    __syncthreads();
    if (tid < 100) {
        int oo2 = tid / 25, q = tid % 25;
        float s = 0.f;
        #pragma unroll
        for (int w = 0; w < 7; w++) s += red[w*100 + oo2*25 + q];
        int o2 = og*4 + oo2;
        if (o2 < 30) part[((size_t)(o2*50 + q) << 6) + b*2 + yh] = s;
    }
}

// ================= Launch B: conv2 + LIF1 + tq2 + g (slot-major state) =========
// grid (13 jg, 32 b), block 192 = (jp:4, xh:2, y:24).
__global__ __launch_bounds__(192) void k_conv2lif(
        const float* __restrict__ w2p, const float* __restrict__ z3,
        const int* __restrict__ cnz4,
        float* __restrict__ v1s, float* __restrict__ i1s,
        float* __restrict__ z4s, float* __restrict__ tq2s,
        float* __restrict__ g_t, int t) {
    __shared__ __attribute__((aligned(16))) float spre[LP];
    __shared__ int sjany[8];
    int jg = blockIdx.x, b = blockIdx.y, tid = threadIdx.x;
    int jb0 = jg*8;
    if (tid < 8) sjany[tid] = 0;
    int jp = tid & 3;
    int j0 = jb0 + jp*2;
    int y = tid >> 3, x0 = ((tid >> 2) & 1)*12;
    int ja = (j0 < 100) ? j0 : 99;
    int jbb = (j0+1 < 100) ? j0+1 : 99;
    float acc0[12], acc1[12];
    #pragma unroll
    for (int xq = 0; xq < 12; xq++) { acc0[xq] = 0.f; acc1[xq] = 0.f; }
    #pragma unroll 1
    for (int c = 0; c < 30; c++) {
        const int* cz = cnz4 + (b*30 + c)*4;
        bool act = (cz[0] | cz[1] | cz[2] | cz[3]) != 0;
        __syncthreads();
        if (act) {
            const float4* src = (const float4*)(z3 + (size_t)(b*30 + c)*LP);
            float4* dst = (float4*)spre;
            for (int i = tid; i < 196; i += 192) dst[i] = src[i];
        }
        __syncthreads();
        if (!act) continue;
        float wa[28], wb[28];
        #pragma unroll
        for (int i = 0; i < 7; i++) {
            ((float4*)wa)[i] = ((const float4*)(w2p + ((size_t)ja*30 + c)*28))[i];
            ((float4*)wb)[i] = ((const float4*)(w2p + ((size_t)jbb*30 + c)*28))[i];
        }
        #pragma unroll
        for (int kh = 0; kh < 5; kh++) {
            float rr[16];
            const float4* r4 = (const float4*)&spre[(y+kh)*HP + x0];
            #pragma unroll
            for (int i = 0; i < 4; i++) ((float4*)rr)[i] = r4[i];
            #pragma unroll
            for (int kw = 0; kw < 5; kw++) {
                float w0 = wa[kh*5+kw], w1 = wb[kh*5+kw];
                #pragma unroll
                for (int xq = 0; xq < 12; xq++) {
                    acc0[xq] = fmaf(w0, rr[xq+kw], acc0[xq]);
                    acc1[xq] = fmaf(w1, rr[xq+kw], acc1[xq]);
                }
            }
        }
    }
    float4* v1p = (float4*)v1s; float4* i1p = (float4*)i1s;
    float4* z4p = (float4*)z4s; float4* t2p = (float4*)tq2s;
    size_t sb2 = ((size_t)(b*13 + jg)*6)*192 + tid;
    bool spk0 = false, spk1 = false;
    #pragma unroll
    for (int jj = 0; jj < 2; jj++) {
        bool anyspk = false;
        #pragma unroll
        for (int i = 0; i < 3; i++) {
            size_t si = sb2 + (size_t)(jj*3 + i)*192;
            float4 v4, c4, t4;
            if (t > 0) { v4 = v1p[si]; c4 = i1p[si]; t4 = t2p[si]; }
            else { v4 = make_float4(0.f,0.f,0.f,0.f); c4 = v4; t4 = v4; }
            float4 vn, in, zn, tn;
            float* vp=(float*)&v4; float* cp=(float*)&c4; float* tp=(float*)&t4;
            float* vnp=(float*)&vn; float* inp=(float*)&in; float* znp=(float*)&zn; float* tnp=(float*)&tn;
            #pragma unroll
            for (int k = 0; k < 4; k++) {
                float a = jj ? acc1[i*4+k] : acc0[i*4+k];
                float vd = vp[k] + DTMEM*(cp[k] - vp[k]);
                float z = (vd > 10.0f) ? 1.0f : 0.0f;
                vnp[k] = (1.0f - z)*vd;
                inp[k] = (cp[k] - DTSYN*cp[k]) + 10.0f*a;
                znp[k] = z;
                tnp[k] = tp[k] + DTTR*(z - tp[k]);
                anyspk = anyspk || (z != 0.f);
            }
            v1p[si] = vn;
            i1p[si] = in;
            z4p[si] = zn;
            t2p[si] = tn;
        }
        if (jj == 0) spk0 = anyspk; else spk1 = anyspk;
    }
    if (spk0 && j0 < 100) atomicOr(&sjany[jp*2], 1);
    if (spk1 && j0+1 < 100) atomicOr(&sjany[jp*2+1], 1);
    __syncthreads();
    if (tid < 8 && jb0 + tid < 100) g_t[b*100 + jb0 + tid] = sjany[tid] ? 1.f : 0.f;
}

// ================= Launch C: z=0 corr mode0, z=1 corr mode1, z=2 w1-apply =========
// grid (13 jg, 30 c, 3), block 192. post reads slot-major (match conv2 geometry).
__global__ __launch_bounds__(192) void k_corr_all(
        const float* __restrict__ tp2, const float* __restrict__ z3,
        const float* __restrict__ z4s, const float* __restrict__ tq2s,
        float* __restrict__ E2P, float* __restrict__ E2M,
        const float* __restrict__ gflag, const int* __restrict__ cnz4,
        float* __restrict__ w1c, const float* __restrict__ part) {
    int MODE = blockIdx.z;
    int tid = threadIdx.x;
    if (MODE == 2) {
        int lb = blockIdx.y*13 + blockIdx.x;
        if (lb >= 8) return;
        int e = lb*192 + tid;
        if (e < 1500) {
            int o = e / 50, r = e % 50, ch = r / 25, p = r % 25;
            float EpS = 0.f, EmS = 0.f;
            #pragma unroll
            for (int s = 0; s < 64; s++) {
                EpS += part[((size_t)(o*50 + p) << 6) + s];
                EmS += part[((size_t)(o*50 + 25 + p) << 6) + s];
            }
            float sign = (ch == 0) ? 1.0f : -1.0f;
            float w = w1c[e];
            float dwp = 0.004f * fmaxf(1.0f - w, 0.0f) * (sign * EpS);
            float dwm = 0.003f * fmaxf(w, 0.0f) * (sign * EmS);
            w1c[e] = fminf(fmaxf(w + dwp - dwm, 0.0f), 1.0f);
        }
        return;
    }
    const float* pre = (MODE == 0) ? tp2 : z3;
    const float4* posts = (const float4*)((MODE == 0) ? z4s : tq2s);
    float* E = (MODE == 0) ? E2P : E2M;
    __shared__ __attribute__((aligned(16))) float spre[LP];
    __shared__ float sflag[8];
    __shared__ float red[3*200];
    int jg = blockIdx.x, c = blockIdx.y;
    int jb0 = jg*8;
    int jp = tid & 3;
    int y = tid >> 3, x0 = ((tid >> 2) & 1)*12;
    float accA[25], accB[25];
    #pragma unroll
    for (int p = 0; p < 25; p++) { accA[p] = 0.f; accB[p] = 0.f; }
    #pragma unroll 1
    for (int b = 0; b < B; b++) {
        __syncthreads();
        if (MODE == 0 && tid < 8)
            sflag[tid] = (jb0 + tid < 100) ? gflag[b*100 + jb0 + tid] : 0.f;
        __syncthreads();
        bool anyb;
        if (MODE == 0)
            anyb = (sflag[0] + sflag[1] + sflag[2] + sflag[3] +
                    sflag[4] + sflag[5] + sflag[6] + sflag[7]) != 0.f;
        else {
            const int* cz = cnz4 + (b*30 + c)*4;
            anyb = (cz[0] | cz[1] | cz[2] | cz[3]) != 0;
        }
        if (anyb) {
            const float4* src = (const float4*)(pre + (size_t)(b*30 + c)*LP);
            float4* dst = (float4*)spre;
            for (int i = tid; i < 196; i += 192) dst[i] = src[i];
        }
        __syncthreads();
        if (!anyb) continue;
        bool mine = true;
        if (MODE == 0) mine = (sflag[jp*2] != 0.f) || (sflag[jp*2+1] != 0.f);
        if (!mine) continue;
        float pA[12], pB[12];
        {
            size_t sb2 = ((size_t)(b*13 + jg)*6)*192 + tid;
            #pragma unroll
            for (int i = 0; i < 3; i++) {
                ((float4*)pA)[i] = posts[sb2 + (size_t)i*192];
                ((float4*)pB)[i] = posts[sb2 + (size_t)(3 + i)*192];
            }
        }
        #pragma unroll
        for (int kh = 0; kh < 5; kh++) {
            float rr[16];
            const float4* r4 = (const float4*)&spre[(y+kh)*HP + x0];
            #pragma unroll
            for (int i = 0; i < 4; i++) ((float4*)rr)[i] = r4[i];
            #pragma unroll
            for (int kw = 0; kw < 5; kw++)
                #pragma unroll
                for (int xq = 0; xq < 12; xq++) {
                    accA[kh*5+kw] = fmaf(rr[xq+kw], pA[xq], accA[kh*5+kw]);
                    accB[kh*5+kw] = fmaf(rr[xq+kw], pB[xq], accB[kh*5+kw]);
                }
        }
    }
    int lane = tid & 63, wave = tid >> 6;
    #pragma unroll
    for (int q = 0; q < 50; q++) {
        float v = (q < 25) ? accA[q] : accB[q-25];
        v += __shfl_xor(v, 4, 64);
        v += __shfl_xor(v, 8, 64);
        v += __shfl_xor(v, 16, 64);
        v += __shfl_xor(v, 32, 64);
        if (lane < 4) red[wave*200 + lane*50 + q] = v;
    }
    __syncthreads();
    if (tid < 200) {
        int jp2 = tid / 50, q = tid % 50;
        float s = red[0*200 + jp2*50 + q] + red[1*200 + jp2*50 + q] + red[2*200 + jp2*50 + q];
        int j = jb0 + jp2*2 + ((q < 25) ? 0 : 1), p = q % 25;
        if (j < 100) E[((size_t)j*30 + c)*25 + p] = s;
    }
}

// ================= k_prep: build padded w2p from INPUT w2 (pad cols loaded-but-unused) ========
__global__ void k_prep(const float* __restrict__ w2, float* __restrict__ w2p) {
    int e = blockIdx.x*blockDim.x + threadIdx.x;
    if (e < 75000) {
        int j = e / 750, r = e % 750, c = r / 25, p = r % 25;
        w2p[((size_t)j*30 + c)*28 + p] = w2[e];
    }
}

// ================= k_fc1b: batched fc1, grid (500 n, 4 t-quarters) =================
__global__ __launch_bounds__(256) void k_fc1b(
        const float* __restrict__ g_all, const float* __restrict__ fcw,
        const float* __restrict__ fcb, float* __restrict__ h_all) {
    __shared__ float red[8][4];
    int n = blockIdx.x, by = blockIdx.y, tid = threadIdx.x;
    const float4* w4 = (const float4*)(fcw + (size_t)n*3200);
    float4 wreg[4];
    #pragma unroll
    for (int i = 0; i < 4; i++) {
        int k = tid + 256*i;
        if (k < 800) wreg[i] = w4[k];
    }
    float accs[8];
    #pragma unroll
    for (int tt = 0; tt < 8; tt++) accs[tt] = 0.f;
    #pragma unroll 1
    for (int tt = 0; tt < 8; tt++) {
        int t = by*8 + tt;
        const float4* g4 = (const float4*)(g_all + (size_t)t*3200);
        float a = 0.f;
        #pragma unroll
        for (int i = 0; i < 4; i++) {
            int k = tid + 256*i;
            if (k < 800) {
                float4 gv = g4[k];
                a = fmaf(gv.x, wreg[i].x, a);
                a = fmaf(gv.y, wreg[i].y, a);
                a = fmaf(gv.z, wreg[i].z, a);
                a = fmaf(gv.w, wreg[i].w, a);
            }
        }
        accs[tt] = a;
    }
    int lane = tid & 63, wid = tid >> 6;
    #pragma unroll
    for (int tt = 0; tt < 8; tt++) {
        float v = accs[tt];
        #pragma unroll
        for (int s = 32; s >= 1; s >>= 1) v += __shfl_down(v, s, 64);
        if (lane == 0) red[tt][wid] = v;
    }
    __syncthreads();
    if (tid < 8)
        h_all[(size_t)(by*8 + tid)*500 + n] =
            red[tid][0] + red[tid][1] + red[tid][2] + red[tid][3] + fcb[n];
}

// ================= k_head_all: LIF2 + LI readout =================
__global__ __launch_bounds__(640) void k_head_all(
        const float* __restrict__ h_all, const float* __restrict__ outw,
        float* __restrict__ out) {
    __shared__ float spk[500];
    __shared__ float vout[10];
    int tid = threadIdx.x;
    int wid = tid >> 6, lane = tid & 63;
    float v2r = 0.f, i2r = 0.f;
    float vor = 0.f, ior = 0.f;
    #pragma unroll 1
    for (int t = 0; t < 32; t++) {
        if (tid < 500) {
            float cur = i2r;
            float vd = v2r + DTMEM*(cur - v2r);
            float z = (vd > 1.0f) ? 1.0f : 0.0f;
            v2r = (1.0f - z)*vd;
            i2r = (cur - DTSYN*cur) + h_all[t*500 + tid];
            spk[tid] = z;
        }
        __syncthreads();
        float acc = 0.f;
        for (int n = lane; n < 500; n += 64)
            acc = fmaf(spk[n], outw[wid*500 + n], acc);
        #pragma unroll
        for (int s = 32; s >= 1; s >>= 1) acc += __shfl_down(acc, s, 64);
        if (lane == 0) {
            float ij = ior + acc;
            float vn = vor + DTMEM*(ij - vor);
            ior = ij - DTSYN*ij;
            vor = vn;
            vout[wid] = vn;
        }
        __syncthreads();
        if (tid < 320) out[(size_t)t*320 + tid] = vout[tid % 10];
        __syncthreads();
    }
}

// ---------------- launcher ----------------
extern "C" void kernel_launch(void* const* d_in, const int* in_sizes, int n_in,
                              void* d_out, int out_size, void* d_ws, size_t ws_size,
                              hipStream_t stream) {
    const float* x    = (const float*)d_in[0];
    const float* b1   = (const float*)d_in[1];
    const float* b2   = (const float*)d_in[2];
    const float* w1   = (const float*)d_in[3];
    const float* w2   = (const float*)d_in[4];
    const float* fcw  = (const float*)d_in[5];
    const float* fcb  = (const float*)d_in[6];
    const float* outw = (const float*)d_in[7];
    float* ws  = (float*)d_ws;
    float* out = (float*)d_out;

    DK dk;
    {
        float g1[25], g2[25], s1 = 0.f, s2 = 0.f;
        for (int i = 0; i < 5; i++)
            for (int j = 0; j < 5; j++) {
                float ai = (float)(i - 2), aj = (float)(j - 2);
                float r2 = ai*ai + aj*aj;
                g1[i*5+j] = expf(-r2/2.0f);
                g2[i*5+j] = expf(-r2/8.0f);
                s1 += g1[i*5+j]; s2 += g2[i*5+j];
            }
        for (int k = 0; k < 25; k++) dk.v[k] = g1[k]/s1 - g2[k]/s2;
    }

    hipMemcpyAsync(ws + OW1, w1, 1500*sizeof(float), hipMemcpyDeviceToDevice, stream);
    k_prep<<<294, 256, 0, stream>>>(w2, ws + OW2P);

    for (int t = 0; t < T; t++) {
        const float* tp1r = ws + ((t & 1) ? OTP1B : OTP1A);
        float*       tp1w = ws + ((t & 1) ? OTP1A : OTP1B);
        k_front<<<dim3(8, 64, 2), 448, 0, stream>>>(
            x, b1, b2, ws+OW1, tp1r, tp1w, ws+OV0, ws+OI0, ws+OTQ1,
            ws+OZ3, ws+OTP2, ws+OP1, (int*)(ws+OCNZ),
            ws+OW2P, ws+OE2P, ws+OE2M, dk, t);
        k_conv2lif<<<dim3(13, 32), 192, 0, stream>>>(
            ws+OW2P, ws+OZ3, (int*)(ws+OCNZ),
            ws+OV1S, ws+OI1S, ws+OZ4S, ws+OTQ2S, ws+OG + (size_t)t*3200, t);
        k_corr_all<<<dim3(13, 30, 3), 192, 0, stream>>>(
            ws+OTP2, ws+OZ3, ws+OZ4S, ws+OTQ2S, ws+OE2P, ws+OE2M,
            ws+OG + (size_t)t*3200, (int*)(ws+OCNZ), ws+OW1, ws+OP1);
    }
    k_fc1b<<<dim3(500, 4), 256, 0, stream>>>(ws+OG, fcw, fcb, ws+OHH);
    k_head_all<<<1, 640, 0, stream>>>(ws+OHH, outw, out);
}

// Round 13
// 1998.371 us; speedup vs baseline: 1.1889x; 1.1889x over previous
//
#include <hip/hip_runtime.h>
#include <math.h>

// ---------------- constants ----------------
#define DTMEM 0.1f   // DT*TAU_MEM_INV
#define DTSYN 0.2f   // DT*TAU_SYN_INV
#define DTTR  0.02f  // DT*TAU_PRE_INV == DT*TAU_POST_INV

static constexpr int B = 32, T = 32;
static constexpr int HD = 60, H1 = 56, HP = 28, H2 = 24;
static constexpr int LD  = HD*HD;   // 3600
static constexpr int L1N = H1*H1;   // 3136
static constexpr int LP  = HP*HP;   // 784
static constexpr int L2N = H2*H2;   // 576

// lif0 state: thread-slot-major [b][og:8][yh:2][i:7][tid:448] float2
static constexpr size_t SST  = (size_t)B*8*2*7*448*2;          // floats (=3,211,264)
// conv2 state: thread-slot-major [b][jg:13][slot:6][tid:192] float4
static constexpr size_t SST2 = (size_t)B*13*6*192*4;           // floats (=1,916,928)

// float offsets: zero region is [OV0, OZEND)
static constexpr size_t OW1   = 0;                             // 1500
static constexpr size_t OV0   = OW1 + 1500;
static constexpr size_t OI0   = OV0   + SST;
static constexpr size_t OTQ1  = OI0   + SST;
static constexpr size_t OTP1A = OTQ1  + SST;                   // [B,60,60]
static constexpr size_t OTP2  = OTP1A + (size_t)B*LD;          // [B,30,28,28]
static constexpr size_t OV1S  = OTP2  + (size_t)B*30*LP;
static constexpr size_t OI1S  = OV1S  + SST2;
static constexpr size_t OTQ2S = OI1S  + SST2;
static constexpr size_t OZEND = OTQ2S + SST2;                  // end of zero region
static constexpr size_t OTP1B = OZEND;                         // [B,60,60] pong
static constexpr size_t OZ3   = OTP1B + (size_t)B*LD;          // [B,30,28,28]
static constexpr size_t OZ4S  = OZ3   + (size_t)B*30*LP;
static constexpr size_t OE2P  = OZ4S  + SST2;                  // [100*30*25]
static constexpr size_t OE2M  = OE2P  + 75000;
static constexpr size_t OP1   = OE2M  + 75000;                 // [30][50][64]
static constexpr size_t OG    = OP1   + 96000;                 // [T][3200]
static constexpr size_t OHH   = OG    + (size_t)T*3200;        // [T][500]
static constexpr size_t OW2P  = OHH   + (size_t)T*500;         // [100][30][28]
static constexpr size_t OCNZ  = OW2P  + 84000;                 // int[960][4]
static constexpr size_t OTOT  = OCNZ  + 3840;

struct DK { float v[25]; };

// ================= Launch A: z=0 front(t) y-half blocks; z=1 w2-apply(t-1) =========
// front: grid (8 og, 64 = b*2+yh, 2), block 448 = (oo:4, xq:4, y:28).
__global__ __launch_bounds__(448) void k_front(
        const float* __restrict__ x, const float* __restrict__ b1,
        const float* __restrict__ b2, const float* __restrict__ w1c,
        const float* __restrict__ tp1r, float* __restrict__ tp1w,
        float* __restrict__ v0, float* __restrict__ i0, float* __restrict__ tq1,
        float* __restrict__ z3, float* __restrict__ tp2,
        float* __restrict__ part, int* __restrict__ cnz4,
        float* __restrict__ w2p, const float* __restrict__ Ep,
        const float* __restrict__ Em, DK dk, int t) {
    if (blockIdx.z == 1) {
        if (t == 0) return;
        int lb = blockIdx.y*8 + blockIdx.x;
        int e = lb*448 + threadIdx.x;
        if (e < 75000) {
            int j = e / 750, r = e % 750, c = r / 25, p = r % 25;
            size_t f = ((size_t)j*30 + c)*28 + p;
            float w = w2p[f];
            float dwp = 0.004f * fmaxf(1.0f - w, 0.0f) * Ep[e];
            float dwm = 0.003f * fmaxf(w, 0.0f) * Em[e];
            w2p[f] = fminf(fmaxf(w + dwp - dwm, 0.0f), 1.0f);
        }
        return;
    }
    __shared__ __attribute__((aligned(16))) float xsh[36*64];   // x rows [y0, y0+36)
    __shared__ __attribute__((aligned(16))) float zsh[32*60];   // DoG rows [y0, y0+32)
    __shared__ __attribute__((aligned(16))) float tsh[32*60];   // tp1 rows [y0, y0+32)
    __shared__ float red[700];                                   // 7 waves x 100
    __shared__ float wd[100];
    __shared__ int sflags[8];
    int og = blockIdx.x, by = blockIdx.y, tid = threadIdx.x;
    int b = by >> 1, yh = by & 1, y0 = yh*28;
    {
        const float4* xs = (const float4*)(x + ((size_t)t*B + b)*4096) + y0*16;
        const float4* ts = (const float4*)(tp1r + (size_t)b*LD) + y0*15;
        for (int i = tid; i < 576; i += 448) ((float4*)xsh)[i] = xs[i];
        for (int i = tid; i < 480; i += 448) ((float4*)tsh)[i] = ts[i];
    }
    if (tid < 100) {
        int oo2 = tid / 25, p = tid % 25;
        int o2 = og*4 + oo2; if (o2 > 29) o2 = 29;
        wd[tid] = w1c[o2*50 + p] - w1c[o2*50 + 25 + p];
    }
    if (tid < 8) sflags[tid] = 0;
    __syncthreads();
    float bias = b1[0] - b2[0];
    // DoG + tp1 trace on local rows (og==0 persists tp1; overlap rows identical)
    for (int idx = tid; idx < 1920; idx += 448) {
        int lr = idx / 60, c = idx % 60;
        float a = 0.f;
        #pragma unroll
        for (int kh = 0; kh < 5; kh++)
            #pragma unroll
            for (int kw = 0; kw < 5; kw++)
                a = fmaf(dk.v[kh*5+kw], xsh[(lr+kh)*64 + c + kw], a);
        float zv = a + bias;
        zsh[idx] = zv;
        float tp = tsh[idx];
        tp = tp + DTTR*(zv - tp);
        tsh[idx] = tp;
        if (og == 0) tp1w[(size_t)b*LD + (y0 + lr)*60 + c] = tp;
    }
    __syncthreads();
    int oo = tid & 3, xq = (tid >> 2) & 3, y = tid >> 4;   // y local [0,28)
    int o = og*4 + oo, x0 = xq*14;
    bool valid = (o < 30);
    float zn[14], tn[14];
    float zs = 0.f, qs = 0.f;
    bool anym = false;
    if (valid) {
        float acc[14];
        #pragma unroll
        for (int k = 0; k < 14; k++) acc[k] = 0.f;
        #pragma unroll
        for (int kh = 0; kh < 5; kh++) {
            float rr[18];
            const float2* r2 = (const float2*)&zsh[(y+kh)*HD + x0];
            #pragma unroll
            for (int i = 0; i < 9; i++) ((float2*)rr)[i] = r2[i];
            #pragma unroll
            for (int kw = 0; kw < 5; kw++) {
                float w = wd[oo*25 + kh*5 + kw];
                #pragma unroll
                for (int k = 0; k < 14; k++) acc[k] = fmaf(w, rr[k+kw], acc[k]);
            }
        }
        // LIF0 + tq1 in slot-major float2 (coalesced)
        float2* v0p = (float2*)v0;
        float2* i0p = (float2*)i0;
        float2* tq1p = (float2*)tq1;
        size_t sb = ((size_t)((b*8 + og)*2 + yh)*7)*448 + tid;
        #pragma unroll
        for (int i = 0; i < 7; i++) {
            float2 v2 = v0p[sb + (size_t)i*448];
            float2 c2 = i0p[sb + (size_t)i*448];
            float2 t2 = tq1p[sb + (size_t)i*448];
            float2 vn, in, tn2;
            #pragma unroll
            for (int k = 0; k < 2; k++) {
                int e = i*2 + k;
                float vv = k ? v2.y : v2.x, cc = k ? c2.y : c2.x, tt = k ? t2.y : t2.x;
                float vd = vv + DTMEM*(cc - vv);
                float z = (vd > 15.0f) ? 1.0f : 0.0f;
                float vo = (1.0f - z)*vd;
                float io_ = (cc - DTSYN*cc) + acc[e];
                float tq = tt + DTTR*(z - tt);
                if (k) { vn.y = vo; in.y = io_; tn2.y = tq; } else { vn.x = vo; in.x = io_; tn2.x = tq; }
                zn[e] = z; tn[e] = tq;
            }
            v0p[sb + (size_t)i*448] = vn;
            i0p[sb + (size_t)i*448] = in;
            tq1p[sb + (size_t)i*448] = tn2;
        }
        #pragma unroll
        for (int k = 0; k < 14; k++) { zs += zn[k]; qs += tn[k]; }
        float mx[7];
        #pragma unroll
        for (int k = 0; k < 7; k++) mx[k] = fmaxf(zn[2*k], zn[2*k+1]);
        #pragma unroll
        for (int k = 0; k < 7; k++) {
            float pm = __shfl_xor(mx[k], 16, 64);   // y-partner (y^1)
            mx[k] = fmaxf(mx[k], pm);
        }
        if ((y & 1) == 0) {
            int py = yh*14 + (y >> 1);
            size_t pb = ((size_t)(b*30 + o)*HP + py)*HP + xq*7;
            #pragma unroll
            for (int k = 0; k < 7; k++) {
                float m = mx[k];
                anym = anym || (m != 0.f);
                z3[pb + k] = m;
                float tpv = tp2[pb + k];
                tp2[pb + k] = tpv + DTTR*(m - tpv);
            }
        }
    }
    if (anym) atomicOr(&sflags[oo*2 + (xq >> 1)], 1);
    int lane = tid & 63, wave = tid >> 6;
    // pass 1: minus correlation (unfold(z0) x tq1_new)
    {
        float a[25];
        #pragma unroll
        for (int p = 0; p < 25; p++) a[p] = 0.f;
        if (valid && qs != 0.f) {
            #pragma unroll
            for (int kh = 0; kh < 5; kh++) {
                float rr[18];
                const float2* r2 = (const float2*)&zsh[(y+kh)*HD + x0];
                #pragma unroll
                for (int i = 0; i < 9; i++) ((float2*)rr)[i] = r2[i];
                #pragma unroll
                for (int kw = 0; kw < 5; kw++)
                    #pragma unroll
                    for (int k = 0; k < 14; k++)
                        a[kh*5+kw] = fmaf(rr[k+kw], tn[k], a[kh*5+kw]);
            }
        }
        #pragma unroll
        for (int q = 0; q < 25; q++) {
            float v = a[q];
            v += __shfl_xor(v, 4, 64);
            v += __shfl_xor(v, 8, 64);
            v += __shfl_xor(v, 16, 64);
            v += __shfl_xor(v, 32, 64);
            if (lane < 4) red[wave*100 + lane*25 + q] = v;
        }
    }
    __syncthreads();
    if (tid < 100) {
        int oo2 = tid / 25, q = tid % 25;
        float s = 0.f;
        #pragma unroll
        for (int w = 0; w < 7; w++) s += red[w*100 + oo2*25 + q];
        int o2 = og*4 + oo2;
        if (o2 < 30) part[((size_t)(o2*50 + 25 + q) << 6) + b*2 + yh] = s;
    }
    if (tid < 8) {
        int o2 = og*4 + (tid >> 1);
        if (o2 < 30) cnz4[(b*30 + o2)*4 + yh*2 + (tid & 1)] = sflags[tid];
    }
    __syncthreads();
    // pass 2: plus correlation (unfold(tp1_new) x z2)
    {
        float a[25];
        #pragma unroll
        for (int p = 0; p < 25; p++) a[p] = 0.f;
        if (valid && zs != 0.f) {
            #pragma unroll
            for (int kh = 0; kh < 5; kh++) {
                float rr[18];
                const float2* r2 = (const float2*)&tsh[(y+kh)*HD + x0];
                #pragma unroll
                for (int i = 0; i < 9; i++) ((float2*)rr)[i] = r2[i];
                #pragma unroll
                for (int kw = 0; kw < 5; kw++)
                    #pragma unroll
                    for (int k = 0; k < 14; k++)
                        a[kh*5+kw] = fmaf(rr[k+kw], zn[k], a[kh*5+kw]);
            }
        }
        #pragma unroll
        for (int q = 0; q < 25; q++) {
            float v = a[q];
            v += __shfl_xor(v, 4, 64);
            v += __shfl_xor(v, 8, 64);
            v += __shfl_xor(v, 16, 64);
            v += __shfl_xor(v, 32, 64);
            if (lane < 4) red[wave*100 + lane*25 + q] = v;
        }
    }
    __syncthreads();
    if (tid < 100) {
        int oo2 = tid / 25, q = tid % 25;
        float s = 0.f;
        #pragma unroll
        for (int w = 0; w < 7; w++) s += red[w*100 + oo2*25 + q];
        int o2 = og*4 + oo2;
        if (o2 < 30) part[((size_t)(o2*50 + q) << 6) + b*2 + yh] = s;
    }
}

// ================= Launch B: conv2 + LIF1 + tq2 + g (slot-major state) =========
// grid (13 jg, 32 b), block 192 = (jp:4, xh:2, y:24).
__global__ __launch_bounds__(192) void k_conv2lif(
        const float* __restrict__ w2p, const float* __restrict__ z3,
        const int* __restrict__ cnz4,
        float* __restrict__ v1s, float* __restrict__ i1s,
        float* __restrict__ z4s, float* __restrict__ tq2s, float* __restrict__ g_t) {
    __shared__ __attribute__((aligned(16))) float spre[LP];
    __shared__ int sjany[8];
    int jg = blockIdx.x, b = blockIdx.y, tid = threadIdx.x;
    int jb0 = jg*8;
    if (tid < 8) sjany[tid] = 0;
    int jp = tid & 3;
    int j0 = jb0 + jp*2;
    int y = tid >> 3, x0 = ((tid >> 2) & 1)*12;
    int ja = (j0 < 100) ? j0 : 99;
    int jbb = (j0+1 < 100) ? j0+1 : 99;
    float acc0[12], acc1[12];
    #pragma unroll
    for (int xq = 0; xq < 12; xq++) { acc0[xq] = 0.f; acc1[xq] = 0.f; }
    #pragma unroll 1
    for (int c = 0; c < 30; c++) {
        const int* cz = cnz4 + (b*30 + c)*4;
        bool act = (cz[0] | cz[1] | cz[2] | cz[3]) != 0;
        __syncthreads();
        if (act) {
            const float4* src = (const float4*)(z3 + (size_t)(b*30 + c)*LP);
            float4* dst = (float4*)spre;
            for (int i = tid; i < 196; i += 192) dst[i] = src[i];
        }
        __syncthreads();
        if (!act) continue;
        float wa[28], wb[28];
        #pragma unroll
        for (int i = 0; i < 7; i++) {
            ((float4*)wa)[i] = ((const float4*)(w2p + ((size_t)ja*30 + c)*28))[i];
            ((float4*)wb)[i] = ((const float4*)(w2p + ((size_t)jbb*30 + c)*28))[i];
        }
        #pragma unroll
        for (int kh = 0; kh < 5; kh++) {
            float rr[16];
            const float4* r4 = (const float4*)&spre[(y+kh)*HP + x0];
            #pragma unroll
            for (int i = 0; i < 4; i++) ((float4*)rr)[i] = r4[i];
            #pragma unroll
            for (int kw = 0; kw < 5; kw++) {
                float w0 = wa[kh*5+kw], w1 = wb[kh*5+kw];
                #pragma unroll
                for (int xq = 0; xq < 12; xq++) {
                    acc0[xq] = fmaf(w0, rr[xq+kw], acc0[xq]);
                    acc1[xq] = fmaf(w1, rr[xq+kw], acc1[xq]);
                }
            }
        }
    }
    float4* v1p = (float4*)v1s; float4* i1p = (float4*)i1s;
    float4* z4p = (float4*)z4s; float4* t2p = (float4*)tq2s;
    size_t sb2 = ((size_t)(b*13 + jg)*6)*192 + tid;
    bool spk0 = false, spk1 = false;
    #pragma unroll
    for (int jj = 0; jj < 2; jj++) {
        bool anyspk = false;
        #pragma unroll
        for (int i = 0; i < 3; i++) {
            size_t si = sb2 + (size_t)(jj*3 + i)*192;
            float4 v4 = v1p[si];
            float4 c4 = i1p[si];
            float4 t4 = t2p[si];
            float4 vn, in, zn, tn;
            float* vp=(float*)&v4; float* cp=(float*)&c4; float* tp=(float*)&t4;
            float* vnp=(float*)&vn; float* inp=(float*)&in; float* znp=(float*)&zn; float* tnp=(float*)&tn;
            #pragma unroll
            for (int k = 0; k < 4; k++) {
                float a = jj ? acc1[i*4+k] : acc0[i*4+k];
                float vd = vp[k] + DTMEM*(cp[k] - vp[k]);
                float z = (vd > 10.0f) ? 1.0f : 0.0f;
                vnp[k] = (1.0f - z)*vd;
                inp[k] = (cp[k] - DTSYN*cp[k]) + 10.0f*a;
                znp[k] = z;
                tnp[k] = tp[k] + DTTR*(z - tp[k]);
                anyspk = anyspk || (z != 0.f);
            }
            v1p[si] = vn;
            i1p[si] = in;
            z4p[si] = zn;
            t2p[si] = tn;
        }
        if (jj == 0) spk0 = anyspk; else spk1 = anyspk;
    }
    if (spk0 && j0 < 100) atomicOr(&sjany[jp*2], 1);
    if (spk1 && j0+1 < 100) atomicOr(&sjany[jp*2+1], 1);
    __syncthreads();
    if (tid < 8 && jb0 + tid < 100) g_t[b*100 + jb0 + tid] = sjany[tid] ? 1.f : 0.f;
}

// ================= Launch C: z=0 corr mode0, z=1 corr mode1, z=2 w1-apply =========
__global__ __launch_bounds__(192) void k_corr_all(
        const float* __restrict__ tp2, const float* __restrict__ z3,
        const float* __restrict__ z4s, const float* __restrict__ tq2s,
        float* __restrict__ E2P, float* __restrict__ E2M,
        const float* __restrict__ gflag, const int* __restrict__ cnz4,
        float* __restrict__ w1c, const float* __restrict__ part) {
    int MODE = blockIdx.z;
    int tid = threadIdx.x;
    if (MODE == 2) {
        int lb = blockIdx.y*13 + blockIdx.x;
        if (lb >= 8) return;
        int e = lb*192 + tid;
        if (e < 1500) {
            int o = e / 50, r = e % 50, ch = r / 25, p = r % 25;
            float EpS = 0.f, EmS = 0.f;
            #pragma unroll
            for (int s = 0; s < 64; s++) {
                EpS += part[((size_t)(o*50 + p) << 6) + s];
                EmS += part[((size_t)(o*50 + 25 + p) << 6) + s];
            }
            float sign = (ch == 0) ? 1.0f : -1.0f;
            float w = w1c[e];
            float dwp = 0.004f * fmaxf(1.0f - w, 0.0f) * (sign * EpS);
            float dwm = 0.003f * fmaxf(w, 0.0f) * (sign * EmS);
            w1c[e] = fminf(fmaxf(w + dwp - dwm, 0.0f), 1.0f);
        }
        return;
    }
    const float* pre = (MODE == 0) ? tp2 : z3;
    const float4* posts = (const float4*)((MODE == 0) ? z4s : tq2s);
    float* E = (MODE == 0) ? E2P : E2M;
    __shared__ __attribute__((aligned(16))) float spre[LP];
    __shared__ float sflag[8];
    __shared__ float red[3*200];
    int jg = blockIdx.x, c = blockIdx.y;
    int jb0 = jg*8;
    int jp = tid & 3;
    int y = tid >> 3, x0 = ((tid >> 2) & 1)*12;
    float accA[25], accB[25];
    #pragma unroll
    for (int p = 0; p < 25; p++) { accA[p] = 0.f; accB[p] = 0.f; }
    #pragma unroll 1
    for (int b = 0; b < B; b++) {
        __syncthreads();
        if (MODE == 0 && tid < 8)
            sflag[tid] = (jb0 + tid < 100) ? gflag[b*100 + jb0 + tid] : 0.f;
        __syncthreads();
        bool anyb;
        if (MODE == 0)
            anyb = (sflag[0] + sflag[1] + sflag[2] + sflag[3] +
                    sflag[4] + sflag[5] + sflag[6] + sflag[7]) != 0.f;
        else {
            const int* cz = cnz4 + (b*30 + c)*4;
            anyb = (cz[0] | cz[1] | cz[2] | cz[3]) != 0;
        }
        if (anyb) {
            const float4* src = (const float4*)(pre + (size_t)(b*30 + c)*LP);
            float4* dst = (float4*)spre;
            for (int i = tid; i < 196; i += 192) dst[i] = src[i];
        }
        __syncthreads();
        if (!anyb) continue;
        bool mine = true;
        if (MODE == 0) mine = (sflag[jp*2] != 0.f) || (sflag[jp*2+1] != 0.f);
        if (!mine) continue;
        float pA[12], pB[12];
        {
            size_t sb2 = ((size_t)(b*13 + jg)*6)*192 + tid;
            #pragma unroll
            for (int i = 0; i < 3; i++) {
                ((float4*)pA)[i] = posts[sb2 + (size_t)i*192];
                ((float4*)pB)[i] = posts[sb2 + (size_t)(3 + i)*192];
            }
        }
        #pragma unroll
        for (int kh = 0; kh < 5; kh++) {
            float rr[16];
            const float4* r4 = (const float4*)&spre[(y+kh)*HP + x0];
            #pragma unroll
            for (int i = 0; i < 4; i++) ((float4*)rr)[i] = r4[i];
            #pragma unroll
            for (int kw = 0; kw < 5; kw++)
                #pragma unroll
                for (int xq = 0; xq < 12; xq++) {
                    accA[kh*5+kw] = fmaf(rr[xq+kw], pA[xq], accA[kh*5+kw]);
                    accB[kh*5+kw] = fmaf(rr[xq+kw], pB[xq], accB[kh*5+kw]);
                }
        }
    }
    int lane = tid & 63, wave = tid >> 6;
    #pragma unroll
    for (int q = 0; q < 50; q++) {
        float v = (q < 25) ? accA[q] : accB[q-25];
        v += __shfl_xor(v, 4, 64);
        v += __shfl_xor(v, 8, 64);
        v += __shfl_xor(v, 16, 64);
        v += __shfl_xor(v, 32, 64);
        if (lane < 4) red[wave*200 + lane*50 + q] = v;
    }
    __syncthreads();
    if (tid < 200) {
        int jp2 = tid / 50, q = tid % 50;
        float s = red[0*200 + jp2*50 + q] + red[1*200 + jp2*50 + q] + red[2*200 + jp2*50 + q];
        int j = jb0 + jp2*2 + ((q < 25) ? 0 : 1), p = q % 25;
        if (j < 100) E[((size_t)j*30 + c)*25 + p] = s;
    }
}

// ================= k_prep: build padded w2p from INPUT w2 =================
__global__ void k_prep(const float* __restrict__ w2, float* __restrict__ w2p) {
    int e = blockIdx.x*blockDim.x + threadIdx.x;
    if (e < 75000) {
        int j = e / 750, r = e % 750, c = r / 25, p = r % 25;
        w2p[((size_t)j*30 + c)*28 + p] = w2[e];
    }
}

// ================= k_fc1b: batched fc1, grid (500 n, 4 t-quarters) =================
__global__ __launch_bounds__(256) void k_fc1b(
        const float* __restrict__ g_all, const float* __restrict__ fcw,
        const float* __restrict__ fcb, float* __restrict__ h_all) {
    __shared__ float red[8][4];
    int n = blockIdx.x, by = blockIdx.y, tid = threadIdx.x;
    const float4* w4 = (const float4*)(fcw + (size_t)n*3200);
    float4 wreg[4];
    #pragma unroll
    for (int i = 0; i < 4; i++) {
        int k = tid + 256*i;
        if (k < 800) wreg[i] = w4[k];
    }
    float accs[8];
    #pragma unroll
    for (int tt = 0; tt < 8; tt++) accs[tt] = 0.f;
    #pragma unroll 1
    for (int tt = 0; tt < 8; tt++) {
        int t = by*8 + tt;
        const float4* g4 = (const float4*)(g_all + (size_t)t*3200);
        float a = 0.f;
        #pragma unroll
        for (int i = 0; i < 4; i++) {
            int k = tid + 256*i;
            if (k < 800) {
                float4 gv = g4[k];
                a = fmaf(gv.x, wreg[i].x, a);
                a = fmaf(gv.y, wreg[i].y, a);
                a = fmaf(gv.z, wreg[i].z, a);
                a = fmaf(gv.w, wreg[i].w, a);
            }
        }
        accs[tt] = a;
    }
    int lane = tid & 63, wid = tid >> 6;
    #pragma unroll
    for (int tt = 0; tt < 8; tt++) {
        float v = accs[tt];
        #pragma unroll
        for (int s = 32; s >= 1; s >>= 1) v += __shfl_down(v, s, 64);
        if (lane == 0) red[tt][wid] = v;
    }
    __syncthreads();
    if (tid < 8)
        h_all[(size_t)(by*8 + tid)*500 + n] =
            red[tid][0] + red[tid][1] + red[tid][2] + red[tid][3] + fcb[n];
}

// ================= k_head_all: LIF2 + LI readout =================
__global__ __launch_bounds__(640) void k_head_all(
        const float* __restrict__ h_all, const float* __restrict__ outw,
        float* __restrict__ out) {
    __shared__ float spk[500];
    __shared__ float vout[10];
    int tid = threadIdx.x;
    int wid = tid >> 6, lane = tid & 63;
    float v2r = 0.f, i2r = 0.f;
    float vor = 0.f, ior = 0.f;
    #pragma unroll 1
    for (int t = 0; t < 32; t++) {
        if (tid < 500) {
            float cur = i2r;
            float vd = v2r + DTMEM*(cur - v2r);
            float z = (vd > 1.0f) ? 1.0f : 0.0f;
            v2r = (1.0f - z)*vd;
            i2r = (cur - DTSYN*cur) + h_all[t*500 + tid];
            spk[tid] = z;
        }
        __syncthreads();
        float acc = 0.f;
        for (int n = lane; n < 500; n += 64)
            acc = fmaf(spk[n], outw[wid*500 + n], acc);
        #pragma unroll
        for (int s = 32; s >= 1; s >>= 1) acc += __shfl_down(acc, s, 64);
        if (lane == 0) {
            float ij = ior + acc;
            float vn = vor + DTMEM*(ij - vor);
            ior = ij - DTSYN*ij;
            vor = vn;
            vout[wid] = vn;
        }
        __syncthreads();
        if (tid < 320) out[(size_t)t*320 + tid] = vout[tid % 10];
        __syncthreads();
    }
}

// ---------------- launcher ----------------
extern "C" void kernel_launch(void* const* d_in, const int* in_sizes, int n_in,
                              void* d_out, int out_size, void* d_ws, size_t ws_size,
                              hipStream_t stream) {
    const float* x    = (const float*)d_in[0];
    const float* b1   = (const float*)d_in[1];
    const float* b2   = (const float*)d_in[2];
    const float* w1   = (const float*)d_in[3];
    const float* w2   = (const float*)d_in[4];
    const float* fcw  = (const float*)d_in[5];
    const float* fcb  = (const float*)d_in[6];
    const float* outw = (const float*)d_in[7];
    float* ws  = (float*)d_ws;
    float* out = (float*)d_out;

    DK dk;
    {
        float g1[25], g2[25], s1 = 0.f, s2 = 0.f;
        for (int i = 0; i < 5; i++)
            for (int j = 0; j < 5; j++) {
                float ai = (float)(i - 2), aj = (float)(j - 2);
                float r2 = ai*ai + aj*aj;
                g1[i*5+j] = expf(-r2/2.0f);
                g2[i*5+j] = expf(-r2/8.0f);
                s1 += g1[i*5+j]; s2 += g2[i*5+j];
            }
        for (int k = 0; k < 25; k++) dk.v[k] = g1[k]/s1 - g2[k]/s2;
    }

    hipMemcpyAsync(ws + OW1, w1, 1500*sizeof(float), hipMemcpyDeviceToDevice, stream);
    hipMemsetAsync(ws + OV0, 0, (OZEND - OV0)*sizeof(float), stream);
    k_prep<<<294, 256, 0, stream>>>(w2, ws + OW2P);

    for (int t = 0; t < T; t++) {
        const float* tp1r = ws + ((t & 1) ? OTP1B : OTP1A);
        float*       tp1w = ws + ((t & 1) ? OTP1A : OTP1B);
        k_front<<<dim3(8, 64, 2), 448, 0, stream>>>(
            x, b1, b2, ws+OW1, tp1r, tp1w, ws+OV0, ws+OI0, ws+OTQ1,
            ws+OZ3, ws+OTP2, ws+OP1, (int*)(ws+OCNZ),
            ws+OW2P, ws+OE2P, ws+OE2M, dk, t);
        k_conv2lif<<<dim3(13, 32), 192, 0, stream>>>(
            ws+OW2P, ws+OZ3, (int*)(ws+OCNZ),
            ws+OV1S, ws+OI1S, ws+OZ4S, ws+OTQ2S, ws+OG + (size_t)t*3200);
        k_corr_all<<<dim3(13, 30, 3), 192, 0, stream>>>(
            ws+OTP2, ws+OZ3, ws+OZ4S, ws+OTQ2S, ws+OE2P, ws+OE2M,
            ws+OG + (size_t)t*3200, (int*)(ws+OCNZ), ws+OW1, ws+OP1);
    }
    k_fc1b<<<dim3(500, 4), 256, 0, stream>>>(ws+OG, fcw, fcb, ws+OHH);
    k_head_all<<<1, 640, 0, stream>>>(ws+OHH, outw, out);
}